// Round 6
// baseline (1105.706 us; speedup 1.0000x reference)
//
#include <hip/hip_runtime.h>
#include <hip/hip_cooperative_groups.h>
#include <cmath>

namespace cg = cooperative_groups;

namespace {
constexpr int Hh = 224, Ww = 448;
constexpr int Tt = 2, Vv = 2, GH = 56, GW = 112;
constexpr int Nn = Vv * GH * GW;       // 12544 gaussians per (t) set
constexpr int TV = Tt * Vv;            // 4 render views
constexpr int TOT = TV * Nn;           // 50176
constexpr int HW = Hh * Ww;            // 100352
constexpr int TILE = 8;                // 8x8 tiles, one wave per tile
constexpr int NTX = Ww / TILE;         // 56
constexpr int NTY = Hh / TILE;         // 28
constexpr int NTILES = TV * NTX * NTY; // 6272
constexpr int CAP_T = 256;             // per-tile list capacity (expected peak ~80)
constexpr int NBLK = 3072;             // cooperative grid: 12 waves/CU (cap 16 via launch_bounds)
constexpr int NTHR = NBLK * 64;        // 196608
constexpr int NWAVE_PRE = TOT / 64;    // 784 preprocess waves (exact)
constexpr int WPV = Nn / 64;           // 196 waves per view (exact)

constexpr size_t RGB_SZ = (size_t)TV * 3 * HW;   // 1204224
constexpr size_t AL_SZ  = (size_t)TV * HW;       // 401408
constexpr size_t OFF_RGB_STA = 0;
constexpr size_t OFF_RGB_DYN = RGB_SZ;
constexpr size_t OFF_RGB_ALL = 2 * RGB_SZ;
constexpr size_t OFF_AL_STA  = 3 * RGB_SZ;
constexpr size_t OFF_AL_DYN  = 3 * RGB_SZ + AL_SZ;
constexpr size_t OFF_AL_ALL  = 3 * RGB_SZ + 2 * AL_SZ;
constexpr size_t OFF_SEM     = 3 * RGB_SZ + 3 * AL_SZ;
constexpr size_t OFF_SM      = OFF_SEM + RGB_SZ;
constexpr size_t OFF_TOUCH   = OFF_SM + 1;

// ---- ws layout (floats) ----
// TOT*12 : per-(view,gaussian) AoS frag {u,v,rsg,z | r,g,b,pk | aa,ad,as,pad}
// then: 784 f wave sigma partials | 784 i wave cnt partials |
//       NTILES i tile counters | NTILES i per-tile touch | NTILES*CAP_T i lists
constexpr size_t WS_FRAG = 0;
constexpr size_t WS_PSUM = (size_t)TOT * 12;
constexpr size_t WS_PCNT = WS_PSUM + NWAVE_PRE;
constexpr size_t WS_TCNT = WS_PCNT + NWAVE_PRE;
constexpr size_t WS_TPB  = WS_TCNT + NTILES;
constexpr size_t WS_LIST = WS_TPB + NTILES;
} // namespace

__device__ inline unsigned long long shfl_xor_u64(unsigned long long x, int m) {
  unsigned int lo = (unsigned int)x, hi = (unsigned int)(x >> 32);
  lo = __shfl_xor(lo, m, 64);
  hi = __shfl_xor(hi, m, 64);
  return ((unsigned long long)hi << 32) | lo;
}

// phase == -1 : cooperative single-launch (grid.sync between phases)
// phase >= 0 : run only that phase (regular-launch fallback)
__global__ __launch_bounds__(64, 4) void fused_k(
    const float* __restrict__ center, const float* __restrict__ scale,
    const float* __restrict__ feat, const float* __restrict__ opac,
    const float* __restrict__ bg, const float* __restrict__ sem,
    const float* __restrict__ intr, const float* __restrict__ c2w,
    const float* __restrict__ fpose, float* __restrict__ ws,
    float* __restrict__ out, int phase) {
#pragma clang fp contract(off)
  cg::grid_group grid = cg::this_grid();
  __shared__ unsigned long long s_key[CAP_T];
  __shared__ float4 s_f0[64], s_f1[64], s_f2[64];

  const int tid = threadIdx.x;          // 0..63, one wave per block
  const int bid = blockIdx.x;
  const int g   = bid * 64 + tid;

  float* Wfrag = ws + WS_FRAG;
  float* Wpsum = ws + WS_PSUM;
  int*   Wpcnt = (int*)(ws + WS_PCNT);
  int*   Wtcnt = (int*)(ws + WS_TCNT);
  int*   Wtpb  = (int*)(ws + WS_TPB);
  int*   Wlist = (int*)(ws + WS_LIST);

  // ================= P0: zero tile counters + sem copy =================
  if (phase == -1 || phase == 0) {
    for (int i = g; i < NTILES; i += NTHR) Wtcnt[i] = 0;
    const float4* s4 = (const float4*)sem;
    float4* d4 = (float4*)(out + OFF_SEM);
    for (int i = g; i < (int)(RGB_SZ / 4); i += NTHR) d4[i] = s4[i];
  }
  if (phase == -1) grid.sync();

  // ================= P1: preprocess (one thread per (view,gaussian)) ====
  if ((phase == -1 || phase == 1) && g < TOT) {
    const int idx = g;
    const int n  = idx % Nn;
    const int tv = idx / Nn;              // wave-uniform (Nn % 64 == 0)
    const int v  = tv % Vv;
    const int t  = tv / Vv;
    const size_t gi = (size_t)t * Nn + n;

    // w2c = inv(c2w[tv]) via fp64 adjugate (register-resident, unrolled).
    // Rotation is exactly identity here -> result is exactly [I | -t],
    // matching the fp32 reference inverse bitwise.
    double m00, m01, m02, m03, m10, m11, m12, m13,
           m20, m21, m22, m23, m30, m31, m32, m33;
    {
      const float* C = c2w + (size_t)tv * 16;
      m00 = C[0];  m01 = C[1];  m02 = C[2];  m03 = C[3];
      m10 = C[4];  m11 = C[5];  m12 = C[6];  m13 = C[7];
      m20 = C[8];  m21 = C[9];  m22 = C[10]; m23 = C[11];
      m30 = C[12]; m31 = C[13]; m32 = C[14]; m33 = C[15];
    }
    const double s0d = m00 * m11 - m10 * m01;
    const double s1d = m00 * m12 - m10 * m02;
    const double s2d = m00 * m13 - m10 * m03;
    const double s3d = m01 * m12 - m11 * m02;
    const double s4d = m01 * m13 - m11 * m03;
    const double s5d = m02 * m13 - m12 * m03;
    const double c5d = m22 * m33 - m32 * m23;
    const double c4d = m21 * m33 - m31 * m23;
    const double c3d = m21 * m32 - m31 * m22;
    const double c2d = m20 * m33 - m30 * m23;
    const double c1d = m20 * m32 - m30 * m22;
    const double c0d = m20 * m31 - m30 * m21;
    const double invdet =
        1.0 / (s0d * c5d - s1d * c4d + s2d * c3d + s3d * c2d - s4d * c1d + s5d * c0d);
    const float M0  = (float)(( m11 * c5d - m12 * c4d + m13 * c3d) * invdet);
    const float M1  = (float)((-m01 * c5d + m02 * c4d - m03 * c3d) * invdet);
    const float M2  = (float)(( m31 * s5d - m32 * s4d + m33 * s3d) * invdet);
    const float M3  = (float)((-m21 * s5d + m22 * s4d - m23 * s3d) * invdet);
    const float M4  = (float)((-m10 * c5d + m12 * c2d - m13 * c1d) * invdet);
    const float M5  = (float)(( m00 * c5d - m02 * c2d + m03 * c1d) * invdet);
    const float M6  = (float)((-m30 * s5d + m32 * s2d - m33 * s1d) * invdet);
    const float M7  = (float)(( m20 * s5d - m22 * s2d + m23 * s1d) * invdet);
    const float M8  = (float)(( m10 * c4d - m11 * c2d + m13 * c0d) * invdet);
    const float M9  = (float)((-m00 * c4d + m01 * c2d - m03 * c0d) * invdet);
    const float M10 = (float)(( m30 * s4d - m31 * s2d + m33 * s0d) * invdet);
    const float M11 = (float)((-m20 * s4d + m21 * s2d - m23 * s0d) * invdet);

    const float c0 = center[gi * 3 + 0], c1 = center[gi * 3 + 1], c2 = center[gi * 3 + 2];
    const float s0 = scale[gi * 3 + 0], s1 = scale[gi * 3 + 1], s2 = scale[gi * 3 + 2];
    const float sf = ((s0 + s1) + s2) / 3.0f;
    const float colr = fminf(fmaxf(feat[gi * 3 + 0], 0.0f), 1.0f);
    const float colg = fminf(fmaxf(feat[gi * 3 + 1], 0.0f), 1.0f);
    const float colb = fminf(fmaxf(feat[gi * 3 + 2], 0.0f), 1.0f);
    const float base = fminf(fmaxf(opac[gi], 0.0f), 1.0f);
    const float dyn  = fminf(fmaxf(1.0f - bg[gi], 0.0f), 1.0f);
    const float aAll = base;
    const float aDyn = base * dyn;
    const float aSta = base * (1.0f - dyn);

    // world = first_pose @ [c,1]  (exact when first_pose == I)
    float wd0, wd1, wd2, wd3;
    wd0 = ((fpose[0]  * c0 + fpose[1]  * c1) + fpose[2]  * c2) + fpose[3]  * 1.0f;
    wd1 = ((fpose[4]  * c0 + fpose[5]  * c1) + fpose[6]  * c2) + fpose[7]  * 1.0f;
    wd2 = ((fpose[8]  * c0 + fpose[9]  * c1) + fpose[10] * c2) + fpose[11] * 1.0f;
    wd3 = ((fpose[12] * c0 + fpose[13] * c1) + fpose[14] * c2) + fpose[15] * 1.0f;

    const float cam0 = ((M0 * wd0 + M1 * wd1) + M2  * wd2) + M3  * wd3;
    const float cam1 = ((M4 * wd0 + M5 * wd1) + M6  * wd2) + M7  * wd3;
    const float cam2 = ((M8 * wd0 + M9 * wd1) + M10 * wd2) + M11 * wd3;
    const bool fin = (fabsf(cam0) <= 3.4028235e38f) && (fabsf(cam1) <= 3.4028235e38f) &&
                     (fabsf(cam2) <= 3.4028235e38f);
    const float z = cam2;
    const float fx = intr[v * 4 + 0], fy = intr[v * 4 + 1];
    const float ppx = intr[v * 4 + 2], ppy = intr[v * 4 + 3];

    bool kept = false;
    float u = 0.0f, vv2 = 0.0f, sig = 0.0f;
    if ((z > 0.001f) && fin) {
      u   = cam0 * fx / z + ppx;          // exact op sequence of the reference
      vv2 = cam1 * fy / z + ppy;
      float tsc = (fx + fy) * 0.5f;
      sig = tsc * fabsf(sf);
      sig = sig / fmaxf(z, 0.001f);
      sig = fminf(fmaxf(sig, 0.75f), 10.0f);
      const bool inb = (u >= -3.0f) && (u <= 450.0f) && (vv2 >= -3.0f) && (vv2 <= 226.0f);
      kept = inb && (aAll > 1e-5f);       // aDyn,aSta <= aAll
    }

    if (kept) {
      const int x0 = (int)floorf(u);
      const int y0 = (int)floorf(vv2);
      const float rc = ceilf(sig * 1.5f); // RADIUS_SCALE
      const int rad = rc < 1.0f ? 1 : (rc > 2.0f ? 2 : (int)rc);
      const int pk = ((x0 + 4) << 16) | ((y0 + 4) << 4) | rad;
      float4* F = (float4*)Wfrag + (size_t)idx * 3;
      F[0] = make_float4(u, vv2, 1.0f / sig, z);   // rsg: sig in [0.75,10]
      F[1] = make_float4(colr, colg, colb, __int_as_float(pk));
      F[2] = make_float4(aAll, aDyn, aSta, 0.0f);
      // scatter binning to 8x8 tiles (bbox interval-overlap)
      const int x_lo = x0 - rad, x_hi = x0 + rad;
      const int y_lo = y0 - rad, y_hi = y0 + rad;
      if (x_hi >= 0 && x_lo < Ww && y_hi >= 0 && y_lo < Hh) {
        const int tx_lo = (x_lo > 0 ? x_lo : 0) >> 3;
        const int tx_hi = (x_hi < Ww - 1 ? x_hi : Ww - 1) >> 3;
        const int ty_lo = (y_lo > 0 ? y_lo : 0) >> 3;
        const int ty_hi = (y_hi < Hh - 1 ? y_hi : Hh - 1) >> 3;
        for (int ty = ty_lo; ty <= ty_hi; ++ty)
          for (int tx = tx_lo; tx <= tx_hi; ++tx) {
            const int tile = (tv * NTY + ty) * NTX + tx;
            const int slot = atomicAdd(&Wtcnt[tile], 1);
            if (slot < CAP_T) Wlist[(size_t)tile * CAP_T + slot] = n;
          }
      }
    }

    // sigma partials: wave shuffle -> ONE plain store per wave (no atomics)
    float sred = kept ? sig : 0.0f;
    int   cred = kept ? 1 : 0;
    #pragma unroll
    for (int off = 32; off > 0; off >>= 1) {
      sred += __shfl_down(sred, off, 64);
      cred += __shfl_down(cred, off, 64);
    }
    if (tid == 0) { Wpsum[bid] = sred; Wpcnt[bid] = cred; }
  }
  if (phase == -1) grid.sync();

  // ================= P2: raster, one wave per 8x8 tile, strided ==========
  if (phase == -1 || phase == 2) {
    for (int tile = bid; tile < NTILES; tile += NBLK) {
      const int tv  = tile / (NTX * NTY);
      const int rem = tile - tv * (NTX * NTY);
      const int tyy = rem / NTX;
      const int txx = rem - tyy * NTX;
      const int px  = txx * TILE + (tid & 7);
      const int py  = tyy * TILE + (tid >> 3);
      const float fpx = (float)px, fpy = (float)py;
      const size_t base = (size_t)tv * Nn;

      const int cnt0 = Wtcnt[tile];
      const int cnt  = cnt0 < CAP_T ? cnt0 : CAP_T;
      const int* mylist = Wlist + (size_t)tile * CAP_T;

      float Aall = 0.0f, Adyn = 0.0f, Asta = 0.0f;
      float Ra = 0.0f, Ga = 0.0f, Ba = 0.0f;
      float Rd = 0.0f, Gd = 0.0f, Bd = 0.0f;
      float Rs = 0.0f, Gs = 0.0f, Bs = 0.0f;

      auto composite = [&](int m) {
        for (int j = 0; j < m; ++j) {
          const float4 f1 = s_f1[j];
          const int pk  = __float_as_int(f1.w);
          const int rad = pk & 15;
          const int y0  = ((pk >> 4) & 0xfff) - 4;
          const int x0  = (pk >> 16) - 4;
          if (abs(px - x0) <= rad && abs(py - y0) <= rad) {
            const float4 f0 = s_f0[j];
            const float du = (f0.x - fpx) * f0.z;
            const float dv = (f0.y - fpy) * f0.z;
            const float gs = __expf(-0.5f * (du * du + dv * dv));
            const float4 f2 = s_f2[j];
            {  // "all": list membership implies aAll > 1e-5
              const float la = fminf(fmaxf(gs * f2.x, 0.0f), 0.999f);
              const float tr = fminf(fmaxf(1.0f - Aall, 0.0f), 1.0f);
              const float ct = la * tr;
              Ra += f1.x * ct; Ga += f1.y * ct; Ba += f1.z * ct;
              Aall = fminf(fmaxf(Aall + ct, 0.0f), 0.999f);
            }
            if (f2.y > 1e-5f) {
              const float la = fminf(fmaxf(gs * f2.y, 0.0f), 0.999f);
              const float tr = fminf(fmaxf(1.0f - Adyn, 0.0f), 1.0f);
              const float ct = la * tr;
              Rd += f1.x * ct; Gd += f1.y * ct; Bd += f1.z * ct;
              Adyn = fminf(fmaxf(Adyn + ct, 0.0f), 0.999f);
            }
            if (f2.z > 1e-5f) {
              const float la = fminf(fmaxf(gs * f2.z, 0.0f), 0.999f);
              const float tr = fminf(fmaxf(1.0f - Asta, 0.0f), 1.0f);
              const float ct = la * tr;
              Rs += f1.x * ct; Gs += f1.y * ct; Bs += f1.z * ct;
              Asta = fminf(fmaxf(Asta + ct, 0.0f), 0.999f);
            }
          }
        }
      };

      if (cnt <= 64) {
        // in-register wave bitonic on (z_bits, n); z>0 so bit order == value
        // order; index tiebreak == stable argsort. No LDS, no barriers.
        unsigned long long key = ~0ULL;
        if (tid < cnt) {
          const unsigned int n = (unsigned int)mylist[tid];
          key = ((unsigned long long)__float_as_uint(Wfrag[(base + n) * 12 + 3]) << 32) | n;
        }
        if (cnt > 1) {
          for (int k = 2; k <= 64; k <<= 1) {
            for (int j = k >> 1; j > 0; j >>= 1) {
              const unsigned long long other = shfl_xor_u64(key, j);
              const bool up = ((tid & k) == 0);
              const bool keep_min = (up == ((tid & j) == 0));
              key = keep_min ? (key < other ? key : other) : (key > other ? key : other);
            }
          }
        }
        if (tid < cnt) {
          const int n = (int)(key & 0xffffffffULL);
          const float4* F = (const float4*)Wfrag + (size_t)(base + n) * 3;
          s_f0[tid] = F[0]; s_f1[tid] = F[1]; s_f2[tid] = F[2];
        }
        __syncthreads();
        composite(cnt);
        __syncthreads();
      } else {
        // LDS bitonic over next pow2 (<= 256), 64 threads striding
        for (int i = tid; i < cnt; i += 64) {
          const unsigned int n = (unsigned int)mylist[i];
          s_key[i] = ((unsigned long long)__float_as_uint(Wfrag[(base + n) * 12 + 3]) << 32) | n;
        }
        int P = 1;
        while (P < cnt) P <<= 1;
        for (int i = cnt + tid; i < P; i += 64) s_key[i] = ~0ULL;
        __syncthreads();
        for (int k = 2; k <= P; k <<= 1) {
          for (int j = k >> 1; j > 0; j >>= 1) {
            for (int i = tid; i < P; i += 64) {
              const int ixj = i ^ j;
              if (ixj > i) {
                const unsigned long long a = s_key[i], b2 = s_key[ixj];
                const bool up = ((i & k) == 0);
                if ((a > b2) == up) { s_key[i] = b2; s_key[ixj] = a; }
              }
            }
            __syncthreads();
          }
        }
        for (int cb = 0; cb < cnt; cb += 64) {
          const int m = min(64, cnt - cb);
          if (tid < m) {
            const int n = (int)(s_key[cb + tid] & 0xffffffffULL);
            const float4* F = (const float4*)Wfrag + (size_t)(base + n) * 3;
            s_f0[tid] = F[0]; s_f1[tid] = F[1]; s_f2[tid] = F[2];
          }
          __syncthreads();
          composite(m);
          __syncthreads();
        }
      }

      // outputs
      const size_t pix = (size_t)py * Ww + px;
      const size_t hw  = (size_t)HW;
      const size_t m3  = (size_t)tv * 3;
      out[OFF_RGB_STA + (m3 + 0) * hw + pix] = fminf(fmaxf(Rs, 0.0f), 1.0f);
      out[OFF_RGB_STA + (m3 + 1) * hw + pix] = fminf(fmaxf(Gs, 0.0f), 1.0f);
      out[OFF_RGB_STA + (m3 + 2) * hw + pix] = fminf(fmaxf(Bs, 0.0f), 1.0f);
      out[OFF_RGB_DYN + (m3 + 0) * hw + pix] = fminf(fmaxf(Rd, 0.0f), 1.0f);
      out[OFF_RGB_DYN + (m3 + 1) * hw + pix] = fminf(fmaxf(Gd, 0.0f), 1.0f);
      out[OFF_RGB_DYN + (m3 + 2) * hw + pix] = fminf(fmaxf(Bd, 0.0f), 1.0f);
      out[OFF_RGB_ALL + (m3 + 0) * hw + pix] = fminf(fmaxf(Ra, 0.0f), 1.0f);
      out[OFF_RGB_ALL + (m3 + 1) * hw + pix] = fminf(fmaxf(Ga, 0.0f), 1.0f);
      out[OFF_RGB_ALL + (m3 + 2) * hw + pix] = fminf(fmaxf(Ba, 0.0f), 1.0f);
      out[OFF_AL_STA + (size_t)tv * hw + pix] = fminf(fmaxf(Asta, 0.0f), 1.0f);
      out[OFF_AL_DYN + (size_t)tv * hw + pix] = fminf(fmaxf(Adyn, 0.0f), 1.0f);
      out[OFF_AL_ALL + (size_t)tv * hw + pix] = fminf(fmaxf(Aall, 0.0f), 1.0f);

      const unsigned long long bal = __ballot(Aall > 1e-6f);
      if (tid == 0) Wtpb[tile] = (int)__popcll(bal);
    }
  }
  if (phase == -1) grid.sync();

  // ================= P3: finalize on block 0 ============================
  if ((phase == -1 || phase == 3) && bid == 0) {
    int acc = 0;
    for (int i = tid; i < NTILES; i += 64) acc += Wtpb[i];
    #pragma unroll
    for (int off = 32; off > 0; off >>= 1) acc += __shfl_down(acc, off, 64);

    float sm = 0.0f;
    for (int tv = 0; tv < TV; ++tv) {
      float ps = 0.0f; int pc = 0;
      for (int w = tv * WPV + tid; w < (tv + 1) * WPV; w += 64) {
        ps += Wpsum[w]; pc += Wpcnt[w];
      }
      #pragma unroll
      for (int off = 32; off > 0; off >>= 1) {
        ps += __shfl_down(ps, off, 64);
        pc += __shfl_down(pc, off, 64);
      }
      if (tid == 0) sm += (pc > 0) ? (ps / (float)(pc > 1 ? pc : 1)) : 0.0f;
    }
    if (tid == 0) {
      out[OFF_SM]    = sm / (float)TV;
      out[OFF_TOUCH] = (float)acc / (float)(HW * TV);
    }
  }
}

extern "C" void kernel_launch(void* const* d_in, const int* in_sizes, int n_in,
                              void* d_out, int out_size, void* d_ws, size_t ws_size,
                              hipStream_t stream) {
  const float* center = (const float*)d_in[0];
  const float* scale  = (const float*)d_in[1];
  const float* feat   = (const float*)d_in[2];
  const float* opac   = (const float*)d_in[3];
  const float* bg     = (const float*)d_in[4];
  const float* sem    = (const float*)d_in[5];
  const float* intr   = (const float*)d_in[6];
  const float* c2w    = (const float*)d_in[7];
  const float* fpose  = (const float*)d_in[8];
  float* out = (float*)d_out;
  float* ws  = (float*)d_ws;

  int phase = -1;
  void* args[] = {(void*)&center, (void*)&scale, (void*)&feat, (void*)&opac,
                  (void*)&bg, (void*)&sem, (void*)&intr, (void*)&c2w,
                  (void*)&fpose, (void*)&ws, (void*)&out, (void*)&phase};
  hipError_t err = hipLaunchCooperativeKernel((const void*)fused_k, dim3(NBLK),
                                              dim3(64), args, 0, stream);
  if (err != hipSuccess) {
    // fallback: 4 regular launches, one phase each (no grid.sync executed)
    for (int p = 0; p < 4; ++p) {
      hipLaunchKernelGGL(fused_k, dim3(NBLK), dim3(64), 0, stream,
                         center, scale, feat, opac, bg, sem, intr, c2w, fpose,
                         ws, out, p);
    }
  }
}

// Round 8
// 190.053 us; speedup vs baseline: 5.8179x; 5.8179x over previous
//
#include <hip/hip_runtime.h>
#include <cmath>

namespace {
constexpr int Hh = 224, Ww = 448;
constexpr int Tt = 2, Vv = 2, GH = 56, GW = 112;
constexpr int Nn = Vv * GH * GW;       // 12544 gaussians per (t) set
constexpr int TV = Tt * Vv;            // 4 render views
constexpr int TOT = TV * Nn;           // 50176
constexpr int HW = Hh * Ww;            // 100352
constexpr int TILE = 8;                // 8x8 tiles, one wave per tile
constexpr int NTX = Ww / TILE;         // 56
constexpr int NTY = Hh / TILE;         // 28
constexpr int NTILES = TV * NTX * NTY; // 6272
constexpr int CAP_T = 256;             // per-tile list capacity (expected peak ~80)
constexpr int NWAVE_PRE = TOT / 64;    // 784 preprocess waves
constexpr int WPV = Nn / 64;           // 196 waves per view

constexpr size_t RGB_SZ = (size_t)TV * 3 * HW;   // 1204224
constexpr size_t AL_SZ  = (size_t)TV * HW;       // 401408
constexpr size_t OFF_RGB_STA = 0;
constexpr size_t OFF_RGB_DYN = RGB_SZ;
constexpr size_t OFF_RGB_ALL = 2 * RGB_SZ;
constexpr size_t OFF_AL_STA  = 3 * RGB_SZ;
constexpr size_t OFF_AL_DYN  = 3 * RGB_SZ + AL_SZ;
constexpr size_t OFF_AL_ALL  = 3 * RGB_SZ + 2 * AL_SZ;
constexpr size_t OFF_SEM     = 3 * RGB_SZ + 3 * AL_SZ;
constexpr size_t OFF_SM      = OFF_SEM + RGB_SZ;
constexpr size_t OFF_TOUCH   = OFF_SM + 1;

// ---- ws layout (floats) ----
// TOT*12 : per-(view,gaussian) AoS frag {u,v,rsg,z | r,g,b,pk | aa,ad,as,pad}
// 784 f  : per-wave sigma partials ; 784 i : per-wave cnt partials
// CTRS (memset to 0 each call): 64 touch slots (stride 16 ints) | done | pad |
//                               NTILES tile counters
// NTILES*CAP_T i : tile lists
constexpr size_t WS_FRAG = 0;
constexpr size_t WS_PSUM = (size_t)TOT * 12;
constexpr size_t WS_PCNT = WS_PSUM + NWAVE_PRE;
constexpr size_t WS_CTRS = WS_PCNT + NWAVE_PRE;
constexpr size_t WS_SLOT = WS_CTRS;                 // 64 slots * 16 ints
constexpr size_t WS_DONE = WS_CTRS + 64 * 16;       // 1 int
constexpr size_t WS_TCNT = WS_DONE + 4;             // NTILES ints
constexpr size_t WS_LIST = WS_TCNT + NTILES;
constexpr size_t N_CTR_BYTES = (WS_LIST - WS_CTRS) * 4;  // memset span
} // namespace

__device__ inline unsigned long long shfl_xor_u64(unsigned long long x, int m) {
  unsigned int lo = (unsigned int)x, hi = (unsigned int)(x >> 32);
  lo = __shfl_xor(lo, m, 64);
  hi = __shfl_xor(hi, m, 64);
  return ((unsigned long long)hi << 32) | lo;
}

__global__ __launch_bounds__(256) void preprocess_k(
    const float* __restrict__ center, const float* __restrict__ scale,
    const float* __restrict__ feat, const float* __restrict__ opac,
    const float* __restrict__ bg, const float* __restrict__ sem,
    const float* __restrict__ intr, const float* __restrict__ c2w,
    const float* __restrict__ fpose, float* __restrict__ ws,
    float* __restrict__ out) {
#pragma clang fp contract(off)
  const int idx = blockIdx.x * 256 + threadIdx.x;
  // Nn = 12544 = 49*256, so tv is uniform across the block.
  const int n  = idx % Nn;
  const int tv = idx / Nn;
  const int v  = tv % Vv;
  const int t  = tv / Vv;
  const size_t gi = (size_t)t * Nn + n;

  float* Wfrag = ws + WS_FRAG;
  float* Wpsum = ws + WS_PSUM;
  int*   Wpcnt = (int*)(ws + WS_PCNT);
  int*   Wtcnt = (int*)(ws + WS_TCNT);
  int*   Wlist = (int*)(ws + WS_LIST);

  // fold the sem copy in (saves a kernel node): 6 float4 per thread
  {
    const float4* s4 = (const float4*)sem;
    float4* d4 = (float4*)(out + OFF_SEM);
    for (int i = idx; i < (int)(RGB_SZ / 4); i += TOT) d4[i] = s4[i];
  }

  // ---- w2c = inv(c2w[tv]) via fp64 adjugate (register-resident, unrolled).
  // Rotation is exactly identity here -> result is exactly [I | -t],
  // matching the fp32 reference inverse bitwise.
  double m00, m01, m02, m03, m10, m11, m12, m13,
         m20, m21, m22, m23, m30, m31, m32, m33;
  {
    const float* C = c2w + (size_t)tv * 16;
    m00 = C[0];  m01 = C[1];  m02 = C[2];  m03 = C[3];
    m10 = C[4];  m11 = C[5];  m12 = C[6];  m13 = C[7];
    m20 = C[8];  m21 = C[9];  m22 = C[10]; m23 = C[11];
    m30 = C[12]; m31 = C[13]; m32 = C[14]; m33 = C[15];
  }
  const double s0d = m00 * m11 - m10 * m01;
  const double s1d = m00 * m12 - m10 * m02;
  const double s2d = m00 * m13 - m10 * m03;
  const double s3d = m01 * m12 - m11 * m02;
  const double s4d = m01 * m13 - m11 * m03;
  const double s5d = m02 * m13 - m12 * m03;
  const double c5d = m22 * m33 - m32 * m23;
  const double c4d = m21 * m33 - m31 * m23;
  const double c3d = m21 * m32 - m31 * m22;
  const double c2d = m20 * m33 - m30 * m23;
  const double c1d = m20 * m32 - m30 * m22;
  const double c0d = m20 * m31 - m30 * m21;
  const double invdet =
      1.0 / (s0d * c5d - s1d * c4d + s2d * c3d + s3d * c2d - s4d * c1d + s5d * c0d);
  const float M0  = (float)(( m11 * c5d - m12 * c4d + m13 * c3d) * invdet);
  const float M1  = (float)((-m01 * c5d + m02 * c4d - m03 * c3d) * invdet);
  const float M2  = (float)(( m31 * s5d - m32 * s4d + m33 * s3d) * invdet);
  const float M3  = (float)((-m21 * s5d + m22 * s4d - m23 * s3d) * invdet);
  const float M4  = (float)((-m10 * c5d + m12 * c2d - m13 * c1d) * invdet);
  const float M5  = (float)(( m00 * c5d - m02 * c2d + m03 * c1d) * invdet);
  const float M6  = (float)((-m30 * s5d + m32 * s2d - m33 * s1d) * invdet);
  const float M7  = (float)(( m20 * s5d - m22 * s2d + m23 * s1d) * invdet);
  const float M8  = (float)(( m10 * c4d - m11 * c2d + m13 * c0d) * invdet);
  const float M9  = (float)((-m00 * c4d + m01 * c2d - m03 * c0d) * invdet);
  const float M10 = (float)(( m30 * s4d - m31 * s2d + m33 * s0d) * invdet);
  const float M11 = (float)((-m20 * s4d + m21 * s2d - m23 * s0d) * invdet);

  const float c0 = center[gi * 3 + 0], c1 = center[gi * 3 + 1], c2 = center[gi * 3 + 2];
  const float s0 = scale[gi * 3 + 0], s1 = scale[gi * 3 + 1], s2 = scale[gi * 3 + 2];
  const float sf = ((s0 + s1) + s2) / 3.0f;
  const float colr = fminf(fmaxf(feat[gi * 3 + 0], 0.0f), 1.0f);
  const float colg = fminf(fmaxf(feat[gi * 3 + 1], 0.0f), 1.0f);
  const float colb = fminf(fmaxf(feat[gi * 3 + 2], 0.0f), 1.0f);
  const float base = fminf(fmaxf(opac[gi], 0.0f), 1.0f);
  const float dyn  = fminf(fmaxf(1.0f - bg[gi], 0.0f), 1.0f);
  const float aAll = base;
  const float aDyn = base * dyn;
  const float aSta = base * (1.0f - dyn);

  // world = first_pose @ [c,1]  (exact when first_pose == I)
  const float wd0 = ((fpose[0]  * c0 + fpose[1]  * c1) + fpose[2]  * c2) + fpose[3];
  const float wd1 = ((fpose[4]  * c0 + fpose[5]  * c1) + fpose[6]  * c2) + fpose[7];
  const float wd2 = ((fpose[8]  * c0 + fpose[9]  * c1) + fpose[10] * c2) + fpose[11];
  const float wd3 = ((fpose[12] * c0 + fpose[13] * c1) + fpose[14] * c2) + fpose[15];

  const float cam0 = ((M0 * wd0 + M1 * wd1) + M2  * wd2) + M3  * wd3;
  const float cam1 = ((M4 * wd0 + M5 * wd1) + M6  * wd2) + M7  * wd3;
  const float cam2 = ((M8 * wd0 + M9 * wd1) + M10 * wd2) + M11 * wd3;
  const bool fin = (fabsf(cam0) <= 3.4028235e38f) && (fabsf(cam1) <= 3.4028235e38f) &&
                   (fabsf(cam2) <= 3.4028235e38f);
  const float z = cam2;
  const float fx = intr[v * 4 + 0], fy = intr[v * 4 + 1];
  const float ppx = intr[v * 4 + 2], ppy = intr[v * 4 + 3];

  bool kept = false;
  float u = 0.0f, vv2 = 0.0f, sig = 0.0f;
  if ((z > 0.001f) && fin) {
    u   = cam0 * fx / z + ppx;            // exact op sequence of the reference
    vv2 = cam1 * fy / z + ppy;
    float tsc = (fx + fy) * 0.5f;
    sig = tsc * fabsf(sf);
    sig = sig / fmaxf(z, 0.001f);
    sig = fminf(fmaxf(sig, 0.75f), 10.0f);
    const bool inb = (u >= -3.0f) && (u <= 450.0f) && (vv2 >= -3.0f) && (vv2 <= 226.0f);
    kept = inb && (aAll > 1e-5f);         // aDyn,aSta <= aAll
  }

  if (kept) {
    const int x0 = (int)floorf(u);
    const int y0 = (int)floorf(vv2);
    const float rc = ceilf(sig * 1.5f);   // RADIUS_SCALE
    const int rad = rc < 1.0f ? 1 : (rc > 2.0f ? 2 : (int)rc);
    const int pk = ((x0 + 4) << 16) | ((y0 + 4) << 4) | rad;
    float4* F = (float4*)Wfrag + (size_t)idx * 3;
    F[0] = make_float4(u, vv2, 1.0f / sig, z);   // rsg: sig in [0.75,10]
    F[1] = make_float4(colr, colg, colb, __int_as_float(pk));
    F[2] = make_float4(aAll, aDyn, aSta, 0.0f);
    // scatter binning to 8x8 tiles (bbox interval-overlap)
    const int x_lo = x0 - rad, x_hi = x0 + rad;
    const int y_lo = y0 - rad, y_hi = y0 + rad;
    if (x_hi >= 0 && x_lo < Ww && y_hi >= 0 && y_lo < Hh) {
      const int tx_lo = (x_lo > 0 ? x_lo : 0) >> 3;
      const int tx_hi = (x_hi < Ww - 1 ? x_hi : Ww - 1) >> 3;
      const int ty_lo = (y_lo > 0 ? y_lo : 0) >> 3;
      const int ty_hi = (y_hi < Hh - 1 ? y_hi : Hh - 1) >> 3;
      for (int ty = ty_lo; ty <= ty_hi; ++ty)
        for (int tx = tx_lo; tx <= tx_hi; ++tx) {
          const int tile = (tv * NTY + ty) * NTX + tx;
          const int slot = atomicAdd(&Wtcnt[tile], 1);
          if (slot < CAP_T) Wlist[(size_t)tile * CAP_T + slot] = n;
        }
    }
  }

  // sigma partials: wave shuffle -> ONE plain store per wave (no atomics)
  float sred = kept ? sig : 0.0f;
  int   cred = kept ? 1 : 0;
  #pragma unroll
  for (int off = 32; off > 0; off >>= 1) {
    sred += __shfl_down(sred, off, 64);
    cred += __shfl_down(cred, off, 64);
  }
  if ((threadIdx.x & 63) == 0) {
    const int w = idx >> 6;
    Wpsum[w] = sred; Wpcnt[w] = cred;
  }
}

// One wave (64 threads) per 8x8 tile. Sort sized to next-pow2(cnt).
__global__ __launch_bounds__(64) void raster_k(float* __restrict__ ws,
                                               float* __restrict__ out) {
#pragma clang fp contract(off)
  __shared__ unsigned long long s_key[CAP_T];
  __shared__ float4 s_f0[64], s_f1[64], s_f2[64];

  const int tid = threadIdx.x;   // 0..63
  const int tv  = blockIdx.z;
  const int px  = blockIdx.x * TILE + (tid & 7);
  const int py  = blockIdx.y * TILE + (tid >> 3);
  const float fpx = (float)px, fpy = (float)py;
  const size_t base = (size_t)tv * Nn;

  const float* Wfrag = ws + WS_FRAG;
  const float* Wpsum = ws + WS_PSUM;
  const int*   Wpcnt = (const int*)(ws + WS_PCNT);
  int*   Wslot = (int*)(ws + WS_SLOT);
  int*   Wdone = (int*)(ws + WS_DONE);
  const int* Wtcnt = (const int*)(ws + WS_TCNT);
  const int* Wlist = (const int*)(ws + WS_LIST);

  const int tile = (tv * NTY + blockIdx.y) * NTX + blockIdx.x;
  const int cnt0 = Wtcnt[tile];
  const int cnt  = cnt0 < CAP_T ? cnt0 : CAP_T;
  const int* mylist = Wlist + (size_t)tile * CAP_T;

  float Aall = 0.0f, Adyn = 0.0f, Asta = 0.0f;
  float Ra = 0.0f, Ga = 0.0f, Ba = 0.0f;
  float Rd = 0.0f, Gd = 0.0f, Bd = 0.0f;
  float Rs = 0.0f, Gs = 0.0f, Bs = 0.0f;

  auto composite = [&](int m) {
    for (int j = 0; j < m; ++j) {
      const float4 f1 = s_f1[j];
      const int pk  = __float_as_int(f1.w);
      const int rad = pk & 15;
      const int y0  = ((pk >> 4) & 0xfff) - 4;
      const int x0  = (pk >> 16) - 4;
      if (abs(px - x0) <= rad && abs(py - y0) <= rad) {
        const float4 f0 = s_f0[j];
        const float du = (f0.x - fpx) * f0.z;
        const float dv = (f0.y - fpy) * f0.z;
        const float gs = __expf(-0.5f * (du * du + dv * dv));
        const float4 f2 = s_f2[j];
        {  // "all": list membership implies aAll > 1e-5
          const float la = fminf(fmaxf(gs * f2.x, 0.0f), 0.999f);
          const float tr = fminf(fmaxf(1.0f - Aall, 0.0f), 1.0f);
          const float ct = la * tr;
          Ra += f1.x * ct; Ga += f1.y * ct; Ba += f1.z * ct;
          Aall = fminf(fmaxf(Aall + ct, 0.0f), 0.999f);
        }
        if (f2.y > 1e-5f) {
          const float la = fminf(fmaxf(gs * f2.y, 0.0f), 0.999f);
          const float tr = fminf(fmaxf(1.0f - Adyn, 0.0f), 1.0f);
          const float ct = la * tr;
          Rd += f1.x * ct; Gd += f1.y * ct; Bd += f1.z * ct;
          Adyn = fminf(fmaxf(Adyn + ct, 0.0f), 0.999f);
        }
        if (f2.z > 1e-5f) {
          const float la = fminf(fmaxf(gs * f2.z, 0.0f), 0.999f);
          const float tr = fminf(fmaxf(1.0f - Asta, 0.0f), 1.0f);
          const float ct = la * tr;
          Rs += f1.x * ct; Gs += f1.y * ct; Bs += f1.z * ct;
          Asta = fminf(fmaxf(Asta + ct, 0.0f), 0.999f);
        }
      }
    }
  };

  if (cnt <= 64) {
    // in-register wave bitonic on (z_bits, n), network sized to P=pow2(cnt):
    // z>0 so bit order == value order; index tiebreak == stable argsort.
    // Lanes >= P never interact with lanes < P (xor with j < P).
    unsigned long long key = ~0ULL;
    if (tid < cnt) {
      const unsigned int n = (unsigned int)mylist[tid];
      key = ((unsigned long long)__float_as_uint(Wfrag[(base + n) * 12 + 3]) << 32) | n;
    }
    if (cnt > 1) {
      int P = 1;
      while (P < cnt) P <<= 1;
      for (int k = 2; k <= P; k <<= 1) {
        for (int j = k >> 1; j > 0; j >>= 1) {
          const unsigned long long other = shfl_xor_u64(key, j);
          const bool up = ((tid & k) == 0);
          const bool keep_min = (up == ((tid & j) == 0));
          key = keep_min ? (key < other ? key : other) : (key > other ? key : other);
        }
      }
    }
    if (tid < cnt) {
      const int n = (int)(key & 0xffffffffULL);
      const float4* F = (const float4*)Wfrag + (size_t)(base + n) * 3;
      s_f0[tid] = F[0]; s_f1[tid] = F[1]; s_f2[tid] = F[2];
    }
    __syncthreads();   // single wave: near-free; orders LDS writes->reads
    composite(cnt);
  } else {
    // LDS bitonic over next pow2 (<= 256), 64 threads striding
    for (int i = tid; i < cnt; i += 64) {
      const unsigned int n = (unsigned int)mylist[i];
      s_key[i] = ((unsigned long long)__float_as_uint(Wfrag[(base + n) * 12 + 3]) << 32) | n;
    }
    int P = 1;
    while (P < cnt) P <<= 1;
    for (int i = cnt + tid; i < P; i += 64) s_key[i] = ~0ULL;
    __syncthreads();
    for (int k = 2; k <= P; k <<= 1) {
      for (int j = k >> 1; j > 0; j >>= 1) {
        for (int i = tid; i < P; i += 64) {
          const int ixj = i ^ j;
          if (ixj > i) {
            const unsigned long long a = s_key[i], b2 = s_key[ixj];
            const bool up = ((i & k) == 0);
            if ((a > b2) == up) { s_key[i] = b2; s_key[ixj] = a; }
          }
        }
        __syncthreads();
      }
    }
    for (int cb = 0; cb < cnt; cb += 64) {
      const int m = min(64, cnt - cb);
      if (tid < m) {
        const int n = (int)(s_key[cb + tid] & 0xffffffffULL);
        const float4* F = (const float4*)Wfrag + (size_t)(base + n) * 3;
        s_f0[tid] = F[0]; s_f1[tid] = F[1]; s_f2[tid] = F[2];
      }
      __syncthreads();
      composite(m);
      __syncthreads();
    }
  }

  // ---- write outputs ----
  const size_t pix = (size_t)py * Ww + px;
  const size_t hw  = (size_t)HW;
  const size_t m3  = (size_t)tv * 3;
  out[OFF_RGB_STA + (m3 + 0) * hw + pix] = fminf(fmaxf(Rs, 0.0f), 1.0f);
  out[OFF_RGB_STA + (m3 + 1) * hw + pix] = fminf(fmaxf(Gs, 0.0f), 1.0f);
  out[OFF_RGB_STA + (m3 + 2) * hw + pix] = fminf(fmaxf(Bs, 0.0f), 1.0f);
  out[OFF_RGB_DYN + (m3 + 0) * hw + pix] = fminf(fmaxf(Rd, 0.0f), 1.0f);
  out[OFF_RGB_DYN + (m3 + 1) * hw + pix] = fminf(fmaxf(Gd, 0.0f), 1.0f);
  out[OFF_RGB_DYN + (m3 + 2) * hw + pix] = fminf(fmaxf(Bd, 0.0f), 1.0f);
  out[OFF_RGB_ALL + (m3 + 0) * hw + pix] = fminf(fmaxf(Ra, 0.0f), 1.0f);
  out[OFF_RGB_ALL + (m3 + 1) * hw + pix] = fminf(fmaxf(Ga, 0.0f), 1.0f);
  out[OFF_RGB_ALL + (m3 + 2) * hw + pix] = fminf(fmaxf(Ba, 0.0f), 1.0f);
  out[OFF_AL_STA + (size_t)tv * hw + pix] = fminf(fmaxf(Asta, 0.0f), 1.0f);
  out[OFF_AL_DYN + (size_t)tv * hw + pix] = fminf(fmaxf(Adyn, 0.0f), 1.0f);
  out[OFF_AL_ALL + (size_t)tv * hw + pix] = fminf(fmaxf(Aall, 0.0f), 1.0f);

  // ---- touch partial + fence-free last-block finalize ----
  const unsigned long long bal = __ballot(Aall > 1e-6f);
  if (tid == 0) {
    const int my = (int)__popcll(bal);
    const int tld = atomicAdd(&Wslot[(tile & 63) * 16], my);
    // force the slot atomic to complete (data dep + waitcnt) before 'done'
    asm volatile("s_waitcnt vmcnt(0)" : : "v"(tld) : "memory");
    const int d = atomicAdd(Wdone, 1);
    if (d == NTILES - 1) {
      // last block: all slot atomics are globally complete. SINGLE-LANE scope:
      // reductions must be scalar loops (R7 bug: __shfl across inactive lanes).
      int acc = 0;
      for (int i = 0; i < 64; ++i) acc += atomicAdd(&Wslot[i * 16], 0);
      float sm = 0.0f;
      for (int tvv = 0; tvv < TV; ++tvv) {
        float ps = 0.0f; int pc = 0;
        for (int w = tvv * WPV; w < (tvv + 1) * WPV; ++w) {
          ps += Wpsum[w]; pc += Wpcnt[w];
        }
        sm += (pc > 0) ? (ps / (float)(pc > 1 ? pc : 1)) : 0.0f;
      }
      out[OFF_SM]    = sm / (float)TV;
      out[OFF_TOUCH] = (float)acc / (float)(HW * TV);
    }
  }
}

extern "C" void kernel_launch(void* const* d_in, const int* in_sizes, int n_in,
                              void* d_out, int out_size, void* d_ws, size_t ws_size,
                              hipStream_t stream) {
  const float* center = (const float*)d_in[0];
  const float* scale  = (const float*)d_in[1];
  const float* feat   = (const float*)d_in[2];
  const float* opac   = (const float*)d_in[3];
  const float* bg     = (const float*)d_in[4];
  const float* sem    = (const float*)d_in[5];
  const float* intr   = (const float*)d_in[6];
  const float* c2w    = (const float*)d_in[7];
  const float* fpose  = (const float*)d_in[8];
  float* out = (float*)d_out;
  float* ws  = (float*)d_ws;

  hipMemsetAsync((void*)(ws + WS_CTRS), 0, N_CTR_BYTES, stream);
  hipLaunchKernelGGL(preprocess_k, dim3(TOT / 256), dim3(256), 0, stream,
                     center, scale, feat, opac, bg, sem, intr, c2w, fpose, ws, out);
  hipLaunchKernelGGL(raster_k, dim3(NTX, NTY, TV), dim3(64), 0, stream, ws, out);
}

// Round 9
// 137.497 us; speedup vs baseline: 8.0417x; 1.3822x over previous
//
#include <hip/hip_runtime.h>
#include <cmath>

namespace {
constexpr int Hh = 224, Ww = 448;
constexpr int Tt = 2, Vv = 2, GH = 56, GW = 112;
constexpr int Nn = Vv * GH * GW;       // 12544 gaussians per (t) set
constexpr int TV = Tt * Vv;            // 4 render views
constexpr int TOT = TV * Nn;           // 50176
constexpr int HW = Hh * Ww;            // 100352
constexpr int TILE = 8;                // 8x8 tiles, one wave per tile
constexpr int NTX = Ww / TILE;         // 56
constexpr int NTY = Hh / TILE;         // 28
constexpr int NTILES = TV * NTX * NTY; // 6272 = 64 classes * 98
constexpr int CAP_T = 256;             // per-tile list capacity (expected peak ~80)
constexpr int NWAVE_PRE = TOT / 64;    // 784 preprocess waves
constexpr int WPV = Nn / 64;           // 196 waves per view
constexpr int NCLS = 64;               // done-tree fanout
constexpr int TILES_PER_CLS = NTILES / NCLS;  // 98

constexpr size_t RGB_SZ = (size_t)TV * 3 * HW;   // 1204224
constexpr size_t AL_SZ  = (size_t)TV * HW;       // 401408
constexpr size_t OFF_RGB_STA = 0;
constexpr size_t OFF_RGB_DYN = RGB_SZ;
constexpr size_t OFF_RGB_ALL = 2 * RGB_SZ;
constexpr size_t OFF_AL_STA  = 3 * RGB_SZ;
constexpr size_t OFF_AL_DYN  = 3 * RGB_SZ + AL_SZ;
constexpr size_t OFF_AL_ALL  = 3 * RGB_SZ + 2 * AL_SZ;
constexpr size_t OFF_SEM     = 3 * RGB_SZ + 3 * AL_SZ;
constexpr size_t OFF_SM      = OFF_SEM + RGB_SZ;
constexpr size_t OFF_TOUCH   = OFF_SM + 1;

// ---- ws layout (floats) ----
// TOT*12 : per-(view,gaussian) AoS frag {u,v,rsg,z | r,g,b,pk | aa,ad,as,pad}
// 784 f  : per-wave sigma partials ; 784 i : per-wave cnt partials
// CTRS (memset to 0 each call): 64 touch slots (stride 16) | 64 class-done
//   (stride 16) | root done | pad | NTILES tile counters
// NTILES*CAP_T i : tile lists
constexpr size_t WS_FRAG  = 0;
constexpr size_t WS_PSUM  = (size_t)TOT * 12;
constexpr size_t WS_PCNT  = WS_PSUM + NWAVE_PRE;
constexpr size_t WS_CTRS  = WS_PCNT + NWAVE_PRE;
constexpr size_t WS_SLOT  = WS_CTRS;                 // 64 slots * 16 ints
constexpr size_t WS_CDONE = WS_CTRS + 64 * 16;       // 64 class counters * 16
constexpr size_t WS_DONE  = WS_CDONE + 64 * 16;      // 1 int
constexpr size_t WS_TCNT  = WS_DONE + 4;             // NTILES ints
constexpr size_t WS_LIST  = WS_TCNT + NTILES;
constexpr size_t N_CTR_BYTES = (WS_LIST - WS_CTRS) * 4;  // memset span
} // namespace

__device__ inline unsigned long long shfl_xor_u64(unsigned long long x, int m) {
  unsigned int lo = (unsigned int)x, hi = (unsigned int)(x >> 32);
  lo = __shfl_xor(lo, m, 64);
  hi = __shfl_xor(hi, m, 64);
  return ((unsigned long long)hi << 32) | lo;
}

__global__ __launch_bounds__(256) void preprocess_k(
    const float* __restrict__ center, const float* __restrict__ scale,
    const float* __restrict__ feat, const float* __restrict__ opac,
    const float* __restrict__ bg, const float* __restrict__ sem,
    const float* __restrict__ intr, const float* __restrict__ c2w,
    const float* __restrict__ fpose, float* __restrict__ ws,
    float* __restrict__ out) {
#pragma clang fp contract(off)
  const int idx = blockIdx.x * 256 + threadIdx.x;
  // Nn = 12544 = 49*256, so tv is uniform across the block.
  const int n  = idx % Nn;
  const int tv = idx / Nn;
  const int v  = tv % Vv;
  const int t  = tv / Vv;
  const size_t gi = (size_t)t * Nn + n;

  float* Wfrag = ws + WS_FRAG;
  float* Wpsum = ws + WS_PSUM;
  int*   Wpcnt = (int*)(ws + WS_PCNT);
  int*   Wtcnt = (int*)(ws + WS_TCNT);
  int*   Wlist = (int*)(ws + WS_LIST);

  // fold the sem copy in (saves a kernel node): 6 float4 per thread
  {
    const float4* s4 = (const float4*)sem;
    float4* d4 = (float4*)(out + OFF_SEM);
    for (int i = idx; i < (int)(RGB_SZ / 4); i += TOT) d4[i] = s4[i];
  }

  // ---- w2c = inv(c2w[tv]) via fp64 adjugate (register-resident, unrolled).
  // Rotation is exactly identity here -> result is exactly [I | -t],
  // matching the fp32 reference inverse bitwise.
  double m00, m01, m02, m03, m10, m11, m12, m13,
         m20, m21, m22, m23, m30, m31, m32, m33;
  {
    const float* C = c2w + (size_t)tv * 16;
    m00 = C[0];  m01 = C[1];  m02 = C[2];  m03 = C[3];
    m10 = C[4];  m11 = C[5];  m12 = C[6];  m13 = C[7];
    m20 = C[8];  m21 = C[9];  m22 = C[10]; m23 = C[11];
    m30 = C[12]; m31 = C[13]; m32 = C[14]; m33 = C[15];
  }
  const double s0d = m00 * m11 - m10 * m01;
  const double s1d = m00 * m12 - m10 * m02;
  const double s2d = m00 * m13 - m10 * m03;
  const double s3d = m01 * m12 - m11 * m02;
  const double s4d = m01 * m13 - m11 * m03;
  const double s5d = m02 * m13 - m12 * m03;
  const double c5d = m22 * m33 - m32 * m23;
  const double c4d = m21 * m33 - m31 * m23;
  const double c3d = m21 * m32 - m31 * m22;
  const double c2d = m20 * m33 - m30 * m23;
  const double c1d = m20 * m32 - m30 * m22;
  const double c0d = m20 * m31 - m30 * m21;
  const double invdet =
      1.0 / (s0d * c5d - s1d * c4d + s2d * c3d + s3d * c2d - s4d * c1d + s5d * c0d);
  const float M0  = (float)(( m11 * c5d - m12 * c4d + m13 * c3d) * invdet);
  const float M1  = (float)((-m01 * c5d + m02 * c4d - m03 * c3d) * invdet);
  const float M2  = (float)(( m31 * s5d - m32 * s4d + m33 * s3d) * invdet);
  const float M3  = (float)((-m21 * s5d + m22 * s4d - m23 * s3d) * invdet);
  const float M4  = (float)((-m10 * c5d + m12 * c2d - m13 * c1d) * invdet);
  const float M5  = (float)(( m00 * c5d - m02 * c2d + m03 * c1d) * invdet);
  const float M6  = (float)((-m30 * s5d + m32 * s2d - m33 * s1d) * invdet);
  const float M7  = (float)(( m20 * s5d - m22 * s2d + m23 * s1d) * invdet);
  const float M8  = (float)(( m10 * c4d - m11 * c2d + m13 * c0d) * invdet);
  const float M9  = (float)((-m00 * c4d + m01 * c2d - m03 * c0d) * invdet);
  const float M10 = (float)(( m30 * s4d - m31 * s2d + m33 * s0d) * invdet);
  const float M11 = (float)((-m20 * s4d + m21 * s2d - m23 * s0d) * invdet);

  const float c0 = center[gi * 3 + 0], c1 = center[gi * 3 + 1], c2 = center[gi * 3 + 2];
  const float s0 = scale[gi * 3 + 0], s1 = scale[gi * 3 + 1], s2 = scale[gi * 3 + 2];
  const float sf = ((s0 + s1) + s2) / 3.0f;
  const float colr = fminf(fmaxf(feat[gi * 3 + 0], 0.0f), 1.0f);
  const float colg = fminf(fmaxf(feat[gi * 3 + 1], 0.0f), 1.0f);
  const float colb = fminf(fmaxf(feat[gi * 3 + 2], 0.0f), 1.0f);
  const float base = fminf(fmaxf(opac[gi], 0.0f), 1.0f);
  const float dyn  = fminf(fmaxf(1.0f - bg[gi], 0.0f), 1.0f);
  const float aAll = base;
  const float aDyn = base * dyn;
  const float aSta = base * (1.0f - dyn);

  // world = first_pose @ [c,1]  (exact when first_pose == I)
  const float wd0 = ((fpose[0]  * c0 + fpose[1]  * c1) + fpose[2]  * c2) + fpose[3];
  const float wd1 = ((fpose[4]  * c0 + fpose[5]  * c1) + fpose[6]  * c2) + fpose[7];
  const float wd2 = ((fpose[8]  * c0 + fpose[9]  * c1) + fpose[10] * c2) + fpose[11];
  const float wd3 = ((fpose[12] * c0 + fpose[13] * c1) + fpose[14] * c2) + fpose[15];

  const float cam0 = ((M0 * wd0 + M1 * wd1) + M2  * wd2) + M3  * wd3;
  const float cam1 = ((M4 * wd0 + M5 * wd1) + M6  * wd2) + M7  * wd3;
  const float cam2 = ((M8 * wd0 + M9 * wd1) + M10 * wd2) + M11 * wd3;
  const bool fin = (fabsf(cam0) <= 3.4028235e38f) && (fabsf(cam1) <= 3.4028235e38f) &&
                   (fabsf(cam2) <= 3.4028235e38f);
  const float z = cam2;
  const float fx = intr[v * 4 + 0], fy = intr[v * 4 + 1];
  const float ppx = intr[v * 4 + 2], ppy = intr[v * 4 + 3];

  bool kept = false;
  float u = 0.0f, vv2 = 0.0f, sig = 0.0f;
  if ((z > 0.001f) && fin) {
    u   = cam0 * fx / z + ppx;            // exact op sequence of the reference
    vv2 = cam1 * fy / z + ppy;
    float tsc = (fx + fy) * 0.5f;
    sig = tsc * fabsf(sf);
    sig = sig / fmaxf(z, 0.001f);
    sig = fminf(fmaxf(sig, 0.75f), 10.0f);
    const bool inb = (u >= -3.0f) && (u <= 450.0f) && (vv2 >= -3.0f) && (vv2 <= 226.0f);
    kept = inb && (aAll > 1e-5f);         // aDyn,aSta <= aAll
  }

  if (kept) {
    const int x0 = (int)floorf(u);
    const int y0 = (int)floorf(vv2);
    const float rc = ceilf(sig * 1.5f);   // RADIUS_SCALE
    const int rad = rc < 1.0f ? 1 : (rc > 2.0f ? 2 : (int)rc);
    const int pk = ((x0 + 4) << 16) | ((y0 + 4) << 4) | rad;
    float4* F = (float4*)Wfrag + (size_t)idx * 3;
    F[0] = make_float4(u, vv2, 1.0f / sig, z);   // rsg: sig in [0.75,10]
    F[1] = make_float4(colr, colg, colb, __int_as_float(pk));
    F[2] = make_float4(aAll, aDyn, aSta, 0.0f);
    // scatter binning to 8x8 tiles (bbox interval-overlap)
    const int x_lo = x0 - rad, x_hi = x0 + rad;
    const int y_lo = y0 - rad, y_hi = y0 + rad;
    if (x_hi >= 0 && x_lo < Ww && y_hi >= 0 && y_lo < Hh) {
      const int tx_lo = (x_lo > 0 ? x_lo : 0) >> 3;
      const int tx_hi = (x_hi < Ww - 1 ? x_hi : Ww - 1) >> 3;
      const int ty_lo = (y_lo > 0 ? y_lo : 0) >> 3;
      const int ty_hi = (y_hi < Hh - 1 ? y_hi : Hh - 1) >> 3;
      for (int ty = ty_lo; ty <= ty_hi; ++ty)
        for (int tx = tx_lo; tx <= tx_hi; ++tx) {
          const int tile = (tv * NTY + ty) * NTX + tx;
          const int slot = atomicAdd(&Wtcnt[tile], 1);
          if (slot < CAP_T) Wlist[(size_t)tile * CAP_T + slot] = n;
        }
    }
  }

  // sigma partials: wave shuffle -> ONE plain store per wave (no atomics)
  float sred = kept ? sig : 0.0f;
  int   cred = kept ? 1 : 0;
  #pragma unroll
  for (int off = 32; off > 0; off >>= 1) {
    sred += __shfl_down(sred, off, 64);
    cred += __shfl_down(cred, off, 64);
  }
  if ((threadIdx.x & 63) == 0) {
    const int w = idx >> 6;
    Wpsum[w] = sred; Wpcnt[w] = cred;
  }
}

// One wave (64 threads) per 8x8 tile. Sort sized to next-pow2(cnt).
__global__ __launch_bounds__(64) void raster_k(float* __restrict__ ws,
                                               float* __restrict__ out) {
#pragma clang fp contract(off)
  __shared__ unsigned long long s_key[CAP_T];
  __shared__ float4 s_f0[64], s_f1[64], s_f2[64];

  const int tid = threadIdx.x;   // 0..63
  const int tv  = blockIdx.z;
  const int px  = blockIdx.x * TILE + (tid & 7);
  const int py  = blockIdx.y * TILE + (tid >> 3);
  const float fpx = (float)px, fpy = (float)py;
  const size_t base = (size_t)tv * Nn;

  const float* Wfrag = ws + WS_FRAG;
  const float* Wpsum = ws + WS_PSUM;
  const int*   Wpcnt = (const int*)(ws + WS_PCNT);
  int*   Wslot  = (int*)(ws + WS_SLOT);
  int*   Wcdone = (int*)(ws + WS_CDONE);
  int*   Wdone  = (int*)(ws + WS_DONE);
  const int* Wtcnt = (const int*)(ws + WS_TCNT);
  const int* Wlist = (const int*)(ws + WS_LIST);

  const int tile = (tv * NTY + blockIdx.y) * NTX + blockIdx.x;
  const int cnt0 = Wtcnt[tile];
  const int cnt  = cnt0 < CAP_T ? cnt0 : CAP_T;
  const int* mylist = Wlist + (size_t)tile * CAP_T;

  float Aall = 0.0f, Adyn = 0.0f, Asta = 0.0f;
  float Ra = 0.0f, Ga = 0.0f, Ba = 0.0f;
  float Rd = 0.0f, Gd = 0.0f, Bd = 0.0f;
  float Rs = 0.0f, Gs = 0.0f, Bs = 0.0f;

  auto composite = [&](int m) {
    for (int j = 0; j < m; ++j) {
      const float4 f1 = s_f1[j];
      const int pk  = __float_as_int(f1.w);
      const int rad = pk & 15;
      const int y0  = ((pk >> 4) & 0xfff) - 4;
      const int x0  = (pk >> 16) - 4;
      if (abs(px - x0) <= rad && abs(py - y0) <= rad) {
        const float4 f0 = s_f0[j];
        const float du = (f0.x - fpx) * f0.z;
        const float dv = (f0.y - fpy) * f0.z;
        const float gs = __expf(-0.5f * (du * du + dv * dv));
        const float4 f2 = s_f2[j];
        {  // "all": list membership implies aAll > 1e-5
          const float la = fminf(fmaxf(gs * f2.x, 0.0f), 0.999f);
          const float tr = fminf(fmaxf(1.0f - Aall, 0.0f), 1.0f);
          const float ct = la * tr;
          Ra += f1.x * ct; Ga += f1.y * ct; Ba += f1.z * ct;
          Aall = fminf(fmaxf(Aall + ct, 0.0f), 0.999f);
        }
        if (f2.y > 1e-5f) {
          const float la = fminf(fmaxf(gs * f2.y, 0.0f), 0.999f);
          const float tr = fminf(fmaxf(1.0f - Adyn, 0.0f), 1.0f);
          const float ct = la * tr;
          Rd += f1.x * ct; Gd += f1.y * ct; Bd += f1.z * ct;
          Adyn = fminf(fmaxf(Adyn + ct, 0.0f), 0.999f);
        }
        if (f2.z > 1e-5f) {
          const float la = fminf(fmaxf(gs * f2.z, 0.0f), 0.999f);
          const float tr = fminf(fmaxf(1.0f - Asta, 0.0f), 1.0f);
          const float ct = la * tr;
          Rs += f1.x * ct; Gs += f1.y * ct; Bs += f1.z * ct;
          Asta = fminf(fmaxf(Asta + ct, 0.0f), 0.999f);
        }
      }
    }
  };

  if (cnt <= 64) {
    // in-register wave bitonic on (z_bits, n), network sized to P=pow2(cnt):
    // z>0 so bit order == value order; index tiebreak == stable argsort.
    unsigned long long key = ~0ULL;
    if (tid < cnt) {
      const unsigned int n = (unsigned int)mylist[tid];
      key = ((unsigned long long)__float_as_uint(Wfrag[(base + n) * 12 + 3]) << 32) | n;
    }
    if (cnt > 1) {
      int P = 1;
      while (P < cnt) P <<= 1;
      for (int k = 2; k <= P; k <<= 1) {
        for (int j = k >> 1; j > 0; j >>= 1) {
          const unsigned long long other = shfl_xor_u64(key, j);
          const bool up = ((tid & k) == 0);
          const bool keep_min = (up == ((tid & j) == 0));
          key = keep_min ? (key < other ? key : other) : (key > other ? key : other);
        }
      }
    }
    if (tid < cnt) {
      const int n = (int)(key & 0xffffffffULL);
      const float4* F = (const float4*)Wfrag + (size_t)(base + n) * 3;
      s_f0[tid] = F[0]; s_f1[tid] = F[1]; s_f2[tid] = F[2];
    }
    __syncthreads();   // single wave: near-free; orders LDS writes->reads
    composite(cnt);
  } else {
    // LDS bitonic over next pow2 (<= 256), 64 threads striding
    for (int i = tid; i < cnt; i += 64) {
      const unsigned int n = (unsigned int)mylist[i];
      s_key[i] = ((unsigned long long)__float_as_uint(Wfrag[(base + n) * 12 + 3]) << 32) | n;
    }
    int P = 1;
    while (P < cnt) P <<= 1;
    for (int i = cnt + tid; i < P; i += 64) s_key[i] = ~0ULL;
    __syncthreads();
    for (int k = 2; k <= P; k <<= 1) {
      for (int j = k >> 1; j > 0; j >>= 1) {
        for (int i = tid; i < P; i += 64) {
          const int ixj = i ^ j;
          if (ixj > i) {
            const unsigned long long a = s_key[i], b2 = s_key[ixj];
            const bool up = ((i & k) == 0);
            if ((a > b2) == up) { s_key[i] = b2; s_key[ixj] = a; }
          }
        }
        __syncthreads();
      }
    }
    for (int cb = 0; cb < cnt; cb += 64) {
      const int m = min(64, cnt - cb);
      if (tid < m) {
        const int n = (int)(s_key[cb + tid] & 0xffffffffULL);
        const float4* F = (const float4*)Wfrag + (size_t)(base + n) * 3;
        s_f0[tid] = F[0]; s_f1[tid] = F[1]; s_f2[tid] = F[2];
      }
      __syncthreads();
      composite(m);
      __syncthreads();
    }
  }

  // ---- write outputs ----
  const size_t pix = (size_t)py * Ww + px;
  const size_t hw  = (size_t)HW;
  const size_t m3  = (size_t)tv * 3;
  out[OFF_RGB_STA + (m3 + 0) * hw + pix] = fminf(fmaxf(Rs, 0.0f), 1.0f);
  out[OFF_RGB_STA + (m3 + 1) * hw + pix] = fminf(fmaxf(Gs, 0.0f), 1.0f);
  out[OFF_RGB_STA + (m3 + 2) * hw + pix] = fminf(fmaxf(Bs, 0.0f), 1.0f);
  out[OFF_RGB_DYN + (m3 + 0) * hw + pix] = fminf(fmaxf(Rd, 0.0f), 1.0f);
  out[OFF_RGB_DYN + (m3 + 1) * hw + pix] = fminf(fmaxf(Gd, 0.0f), 1.0f);
  out[OFF_RGB_DYN + (m3 + 2) * hw + pix] = fminf(fmaxf(Bd, 0.0f), 1.0f);
  out[OFF_RGB_ALL + (m3 + 0) * hw + pix] = fminf(fmaxf(Ra, 0.0f), 1.0f);
  out[OFF_RGB_ALL + (m3 + 1) * hw + pix] = fminf(fmaxf(Ga, 0.0f), 1.0f);
  out[OFF_RGB_ALL + (m3 + 2) * hw + pix] = fminf(fmaxf(Ba, 0.0f), 1.0f);
  out[OFF_AL_STA + (size_t)tv * hw + pix] = fminf(fmaxf(Asta, 0.0f), 1.0f);
  out[OFF_AL_DYN + (size_t)tv * hw + pix] = fminf(fmaxf(Adyn, 0.0f), 1.0f);
  out[OFF_AL_ALL + (size_t)tv * hw + pix] = fminf(fmaxf(Aall, 0.0f), 1.0f);

  // ---- touch partial + 2-level fence-free finalize ----
  // (R8 lesson: a single flat done counter = 6272 same-address atomics at
  //  ~17.5 ns each = 110 us serialization. Tree: max 98 per address.)
  const unsigned long long bal = __ballot(Aall > 1e-6f);
  if (tid == 0) {
    const int my  = (int)__popcll(bal);
    const int cls = tile & (NCLS - 1);
    const int tld = atomicAdd(&Wslot[cls * 16], my);
    // force slot atomic completion (data dep + waitcnt) before class-done
    asm volatile("s_waitcnt vmcnt(0)" : : "v"(tld) : "memory");
    const int cd = atomicAdd(&Wcdone[cls * 16], 1);
    if (cd == TILES_PER_CLS - 1) {      // last block of this class
      asm volatile("s_waitcnt vmcnt(0)" : : "v"(cd) : "memory");
      const int d = atomicAdd(Wdone, 1);
      if (d == NCLS - 1) {
        // all classes done => all slot atomics complete. SINGLE-LANE scope:
        // scalar loops only (R7 bug: __shfl across inactive lanes).
        int acc = 0;
        for (int i = 0; i < NCLS; ++i) acc += atomicAdd(&Wslot[i * 16], 0);
        float sm = 0.0f;
        for (int tvv = 0; tvv < TV; ++tvv) {
          float ps = 0.0f; int pc = 0;
          for (int w = tvv * WPV; w < (tvv + 1) * WPV; ++w) {
            ps += Wpsum[w]; pc += Wpcnt[w];
          }
          sm += (pc > 0) ? (ps / (float)(pc > 1 ? pc : 1)) : 0.0f;
        }
        out[OFF_SM]    = sm / (float)TV;
        out[OFF_TOUCH] = (float)acc / (float)(HW * TV);
      }
    }
  }
}

extern "C" void kernel_launch(void* const* d_in, const int* in_sizes, int n_in,
                              void* d_out, int out_size, void* d_ws, size_t ws_size,
                              hipStream_t stream) {
  const float* center = (const float*)d_in[0];
  const float* scale  = (const float*)d_in[1];
  const float* feat   = (const float*)d_in[2];
  const float* opac   = (const float*)d_in[3];
  const float* bg     = (const float*)d_in[4];
  const float* sem    = (const float*)d_in[5];
  const float* intr   = (const float*)d_in[6];
  const float* c2w    = (const float*)d_in[7];
  const float* fpose  = (const float*)d_in[8];
  float* out = (float*)d_out;
  float* ws  = (float*)d_ws;

  hipMemsetAsync((void*)(ws + WS_CTRS), 0, N_CTR_BYTES, stream);
  hipLaunchKernelGGL(preprocess_k, dim3(TOT / 256), dim3(256), 0, stream,
                     center, scale, feat, opac, bg, sem, intr, c2w, fpose, ws, out);
  hipLaunchKernelGGL(raster_k, dim3(NTX, NTY, TV), dim3(64), 0, stream, ws, out);
}